// Round 3
// baseline (999.600 us; speedup 1.0000x reference)
//
#include <hip/hip_runtime.h>

typedef __attribute__((ext_vector_type(8))) short short8v;
typedef __attribute__((ext_vector_type(4))) float f32x4;
typedef __attribute__((ext_vector_type(4))) unsigned int uint4v;
typedef unsigned short u16;

__device__ __forceinline__ u16 f2bf(float f) {
  unsigned u = __float_as_uint(f);
  u += 0x7FFFu + ((u >> 16) & 1u);
  return (u16)(u >> 16);
}
__device__ __forceinline__ short8v ld8(const u16* p) {
  return *reinterpret_cast<const short8v*>(p);
}
__device__ __forceinline__ float fsig(float x) { return 1.f / (1.f + __expf(-x)); }
__device__ __forceinline__ float ftanh(float x) {
  float e = __expf(2.f * x);
  return 1.f - 2.f / (e + 1.f);
}

// ---------------- weight packing: fp32 NCHW-kernels -> bf16 MFMA-B layout ----
__global__ void k_pack(const float* __restrict__ We0, const float* __restrict__ We1,
                       const float* __restrict__ Wd,
                       u16* __restrict__ Wh0p, u16* __restrict__ Wx0p,
                       u16* __restrict__ Wx1p, u16* __restrict__ Wh1p,
                       u16* __restrict__ Whdp, u16* __restrict__ Wxdp) {
  int i = blockIdx.x * 256 + threadIdx.x;   // total 155648
  if (i < 36864) {
    int s = i >> 12, co = (i >> 5) & 127, ci = i & 31;
    Wh0p[i] = f2bf(We0[(co * 35 + 3 + ci) * 9 + s]);
  } else if (i < 40960) {
    int j = i - 36864; int co = j >> 5, k = j & 31;
    Wx0p[j] = (k < 27) ? f2bf(We0[(co * 35 + (k % 3)) * 9 + (k / 3)]) : (u16)0;
  } else if (i < 77824) {
    int j = i - 40960; int s = j >> 12, co = (j >> 5) & 127, ci = j & 31;
    Wx1p[j] = f2bf(We1[(co * 64 + ci) * 9 + s]);
  } else if (i < 114688) {
    int j = i - 77824; int s = j >> 12, co = (j >> 5) & 127, ci = j & 31;
    Wh1p[j] = f2bf(We1[(co * 64 + 32 + ci) * 9 + s]);
  } else if (i < 151552) {
    int j = i - 114688; int s = j >> 12, co = (j >> 5) & 127, ci = j & 31;
    Whdp[j] = f2bf(Wd[(co * 35 + 3 + ci) * 9 + s]);
  } else if (i < 155648) {
    int j = i - 151552; int co = j >> 5, k = j & 31;
    Wxdp[j] = (k < 27) ? f2bf(Wd[(co * 35 + (k % 3)) * 9 + (k / 3)]) : (u16)0;
  }
}

// ---------------- im2col of x for ALL frames: [t][b][y][x][32] bf16 ----------
__global__ void k_im2col(const float* __restrict__ x, u16* __restrict__ out) {
  int p = blockIdx.x * 256 + threadIdx.x;   // 786432 = 24*8*4096
  int t = p >> 15;
  int rem = p & 32767;
  int b = rem >> 12;
  int yy = (rem >> 6) & 63;
  int xx = rem & 63;
  __align__(16) u16 buf[32];
#pragma unroll
  for (int k = 27; k < 32; k++) buf[k] = 0;
  const float* xb = x + ((size_t)(b * 24 + t)) * 3 * 4096;
#pragma unroll
  for (int ky = 0; ky < 3; ky++) {
    int ys = yy + ky - 1;
    bool yok = (unsigned)ys < 64u;
#pragma unroll
    for (int kx = 0; kx < 3; kx++) {
      int xs = xx + kx - 1;
      bool ok = yok && ((unsigned)xs < 64u);
#pragma unroll
      for (int ci = 0; ci < 3; ci++) {
        float v = ok ? xb[(size_t)ci * 4096 + ys * 64 + xs] : 0.f;
        buf[(ky * 3 + kx) * 3 + ci] = f2bf(v);
      }
    }
  }
  uint4v* dst = (uint4v*)(out + (size_t)p * 32);
  const uint4v* s = (const uint4v*)buf;
  dst[0] = s[0]; dst[1] = s[1]; dst[2] = s[2]; dst[3] = s[3];
}

__global__ void k_zero(uint4v* __restrict__ p, int n) {
  int i = blockIdx.x * 256 + threadIdx.x;
  if (i < n) p[i] = (uint4v)0u;
}

// ---------------- fused ConvLSTM step body ----------------------------------
// M-split waves: wave w owns px [w*16, w*16+16), ALL 128 gate channels.
// acc[nt] = D-tile for co in [nt*16, nt*16+16). Lane (g,lr) holds, for
// px = w*16+g*4+j, channel co = nt*16+lr -> gates i/f/o/g of ch=lr are
// acc[0/2/4/6][j], of ch=lr+16 are acc[1/3/5/7][j]: fully thread-local.
// LDS: staging only ([3][66][32] bf16 per operand, x-padded, zero borders).
template <int MODE>
__device__ __forceinline__ void step_body(
    char* smem, int bid,
    const u16* __restrict__ xA, const u16* __restrict__ Wx,
    const u16* __restrict__ Wh, const float* __restrict__ bias,
    const u16* __restrict__ hprev, const float* __restrict__ cprev,
    u16* __restrict__ hout, float* __restrict__ cout,
    float* __restrict__ hdec) {
  const int tid = threadIdx.x;
  const int b = bid >> 6;
  const int y = bid & 63;
  const int l = tid & 63;
  const int w = tid >> 6;
  const int lr = l & 15;
  const int g = l >> 4;

  u16* sm_h = (u16*)smem;                 // [3][66][32] = 12672 B
  u16* sm_x = (u16*)(smem + 12672);       // MODE1 only

  // zero the 1-px pads on both ends of each staged row
  const int npad = (MODE == 1) ? 48 : 24;
  if (tid < npad) {
    int op = tid / 24, q = tid % 24;
    int r = q >> 3, qq = q & 7;
    u16* base = (op ? sm_x : sm_h) + r * 2112 + ((qq < 4) ? 0 : 65 * 32);
    ((uint4v*)base)[qq & 3] = (uint4v)0u;
  }
#pragma unroll
  for (int i = tid; i < 768; i += 256) {
    int r = i >> 8, j = i & 255;
    int ys = y + r - 1;
    uint4v v = (uint4v)0u;
    if ((unsigned)ys < 64u)
      v = *(const uint4v*)(hprev + ((size_t)((b * 64 + ys) * 64)) * 32 + j * 8);
    *(uint4v*)(sm_h + r * 2112 + 32 + j * 8) = v;
    if (MODE == 1) {
      uint4v vx = (uint4v)0u;
      if ((unsigned)ys < 64u)
        vx = *(const uint4v*)(xA + ((size_t)((b * 64 + ys) * 64)) * 32 + j * 8);
      *(uint4v*)(sm_x + r * 2112 + 32 + j * 8) = vx;
    }
  }
  __syncthreads();

  f32x4 acc[8];
#pragma unroll
  for (int i = 0; i < 8; i++) acc[i] = (f32x4)0.f;

  if (MODE == 0 || MODE == 2) {
    // im2col K=32 chunk: A row = px, k padded to 32
    short8v A = ld8(xA + (size_t)((b << 12) + (y << 6) + (w << 4) + lr) * 32 + g * 8);
#pragma unroll
    for (int nt = 0; nt < 8; nt++) {
      short8v B = ld8(Wx + (size_t)(nt * 16 + lr) * 32 + g * 8);
      acc[nt] = __builtin_amdgcn_mfma_f32_16x16x32_bf16(A, B, acc[nt], 0, 0, 0);
    }
  }

  auto do_shifts = [&](const u16* sm, const u16* __restrict__ W) {
#pragma unroll
    for (int s = 0; s < 9; s++) {
      const int r = s / 3, dx = s % 3 - 1;
      int ys = y + r - 1;
      if ((unsigned)ys >= 64u) continue;   // block-uniform: border row is zero
      short8v A = ld8(sm + r * 2112 + (w * 16 + lr + dx + 1) * 32 + g * 8);
      const u16* wb = W + (size_t)(s * 128 + lr) * 32 + g * 8;
#pragma unroll
      for (int nt = 0; nt < 8; nt++) {
        short8v B = ld8(wb + nt * 512);
        acc[nt] = __builtin_amdgcn_mfma_f32_16x16x32_bf16(A, B, acc[nt], 0, 0, 0);
      }
    }
  };

  if (MODE == 1) do_shifts(sm_x, Wx);
  do_shifts(sm_h, Wh);

  // gates fully in-register
  float bI0 = bias[lr],      bF0 = bias[lr + 32], bO0 = bias[lr + 64], bG0 = bias[lr + 96];
  float bI1 = bias[lr + 16], bF1 = bias[lr + 48], bO1 = bias[lr + 80], bG1 = bias[lr + 112];
#pragma unroll
  for (int j = 0; j < 4; j++) {
    int px = w * 16 + g * 4 + j;
    size_t base = ((size_t)((b * 64 + y) * 64 + px)) * 32;
    {
      float cold = cprev[base + lr];
      float cn = fsig(acc[2][j] + bF0) * cold + fsig(acc[0][j] + bI0) * ftanh(acc[6][j] + bG0);
      float hn = fsig(acc[4][j] + bO0) * ftanh(cn);
      cout[base + lr] = cn;
      hout[base + lr] = f2bf(hn);
      if (MODE == 2) hdec[((size_t)(b * 32 + lr) * 64 + y) * 64 + px] = hn;
    }
    {
      float cold = cprev[base + lr + 16];
      float cn = fsig(acc[3][j] + bF1) * cold + fsig(acc[1][j] + bI1) * ftanh(acc[7][j] + bG1);
      float hn = fsig(acc[5][j] + bO1) * ftanh(cn);
      cout[base + lr + 16] = cn;
      hout[base + lr + 16] = f2bf(hn);
      if (MODE == 2) hdec[((size_t)(b * 32 + lr + 16) * 64 + y) * 64 + px] = hn;
    }
  }
}

// dual-layer launch: blocks 0..511 = layer0 step t, 512..1023 = layer1 step t-1
// layer0's hidden state IS hs0[t-1] (no separate ping-pong).
__global__ __launch_bounds__(256) void k_dual(
    int t, const u16* __restrict__ imc, u16* __restrict__ hs0,
    const u16* __restrict__ zpage, float* c0, u16* h1a, u16* h1b, float* c1,
    const u16* __restrict__ Wx0, const u16* __restrict__ Wh0, const float* __restrict__ be0,
    const u16* __restrict__ Wx1, const u16* __restrict__ Wh1, const float* __restrict__ be1) {
  __shared__ __align__(16) char smem[25344];
  int bid = blockIdx.x;
  if (bid < 512) {
    if (t >= 24) return;
    const u16* hp = (t == 0) ? zpage : hs0 + (size_t)(t - 1) * 1048576;
    step_body<0>(smem, bid, imc + (size_t)t * 1048576, Wx0, Wh0, be0, hp, c0,
                 hs0 + (size_t)t * 1048576, c0, nullptr);
  } else {
    int tt = t - 1;
    if (tt < 0) return;
    const u16* hp = (tt & 1) ? h1b : h1a;
    u16* hn = (tt & 1) ? h1a : h1b;
    step_body<1>(smem, bid - 512, hs0 + (size_t)tt * 1048576, Wx1, Wh1, be1, hp,
                 c1, hn, c1, nullptr);
  }
}

__global__ __launch_bounds__(256) void k_dec(
    const u16* __restrict__ imc23, const u16* __restrict__ Wxd,
    const u16* __restrict__ Whd, const float* __restrict__ bd,
    const u16* __restrict__ h1fin, const float* __restrict__ c1,
    u16* __restrict__ hscr, float* __restrict__ cscr, float* __restrict__ hdec) {
  __shared__ __align__(16) char smem[12672];
  step_body<2>(smem, blockIdx.x, imc23, Wxd, Whd, bd, h1fin, c1, hscr, cscr, hdec);
}

// ---------------- FC head ---------------------------------------------------
// fc1: grid (16 ng, 128 ks); block: n in [ng*16,+16) (4 n-rows per wave),
// k in [ks*1024,+1024). feat slice staged once in LDS; weight is the only
// global stream (fully-unrolled 16 x 16B loads in flight per lane).
__global__ __launch_bounds__(256) void k_fc1(const float* __restrict__ w,
                                             const float* __restrict__ feat,
                                             float* __restrict__ partial) {
  __shared__ float fsm[8][1024];   // 32 KB
  const int ng = blockIdx.x, ks = blockIdx.y;
  const int tid = threadIdx.x;
  const float* fb = feat + (size_t)ks * 1024;
  for (int i = tid; i < 2048; i += 256) {
    int bb = i >> 8, kk = (i & 255) << 2;
    *(f32x4*)&fsm[bb][kk] = *(const f32x4*)(fb + (size_t)bb * 131072 + kk);
  }
  __syncthreads();
  const int wv = tid >> 6, lane = tid & 63;
  const int n0 = ng * 16 + wv * 4;
  const float* wr = w + (size_t)n0 * 131072 + (size_t)ks * 1024;
  float acc[4][8];
#pragma unroll
  for (int i = 0; i < 4; i++)
#pragma unroll
    for (int j = 0; j < 8; j++) acc[i][j] = 0.f;
#pragma unroll
  for (int it = 0; it < 4; it++) {
    int k = it * 256 + lane * 4;
    f32x4 w0 = *(const f32x4*)(wr + k);
    f32x4 w1 = *(const f32x4*)(wr + 131072 + k);
    f32x4 w2 = *(const f32x4*)(wr + 262144 + k);
    f32x4 w3 = *(const f32x4*)(wr + 393216 + k);
#pragma unroll
    for (int bb = 0; bb < 8; bb++) {
      f32x4 fv = *(const f32x4*)&fsm[bb][k];
      acc[0][bb] += w0[0] * fv[0] + w0[1] * fv[1] + w0[2] * fv[2] + w0[3] * fv[3];
      acc[1][bb] += w1[0] * fv[0] + w1[1] * fv[1] + w1[2] * fv[2] + w1[3] * fv[3];
      acc[2][bb] += w2[0] * fv[0] + w2[1] * fv[1] + w2[2] * fv[2] + w2[3] * fv[3];
      acc[3][bb] += w3[0] * fv[0] + w3[1] * fv[1] + w3[2] * fv[2] + w3[3] * fv[3];
    }
  }
#pragma unroll
  for (int nn = 0; nn < 4; nn++)
#pragma unroll
    for (int bb = 0; bb < 8; bb++) {
      float v = acc[nn][bb];
#pragma unroll
      for (int m = 32; m >= 1; m >>= 1) v += __shfl_xor(v, m, 64);
      if (lane == 0) partial[((size_t)ks * 8 + bb) * 256 + n0 + nn] = v;
    }
}

__global__ void k_fc1_fin(const float* __restrict__ partial,
                          const float* __restrict__ b1, float* __restrict__ hdn) {
  int i = blockIdx.x * 256 + threadIdx.x;  // 2048
  if (i >= 2048) return;
  int b = i >> 8, n = i & 255;
  float v = b1[n];
  for (int ks = 0; ks < 128; ks++) v += partial[((size_t)ks * 8 + b) * 256 + n];
  hdn[i] = fmaxf(v, 0.f);
}

__global__ void k_fc2(const float* __restrict__ hdn, const float* __restrict__ w2,
                      const float* __restrict__ b2, float* __restrict__ out) {
  int i = blockIdx.x * 256 + threadIdx.x;  // 776 = 8*97
  if (i >= 776) return;
  int b = i / 97, m = i % 97;
  const float* h = hdn + b * 256;
  const float* wr = w2 + m * 256;
  float v = b2[m];
  for (int k = 0; k < 256; k++) v += h[k] * wr[k];
  out[i] = v;
}

// ---------------- launcher ---------------------------------------------------
extern "C" void kernel_launch(void* const* d_in, const int* in_sizes, int n_in,
                              void* d_out, int out_size, void* d_ws, size_t ws_size,
                              hipStream_t stream) {
  const float* x   = (const float*)d_in[0];
  const float* We0 = (const float*)d_in[1];
  const float* be0 = (const float*)d_in[2];
  const float* We1 = (const float*)d_in[3];
  const float* be1 = (const float*)d_in[4];
  const float* Wd  = (const float*)d_in[5];
  const float* bd  = (const float*)d_in[6];
  const float* f1w = (const float*)d_in[7];
  const float* f1b = (const float*)d_in[8];
  const float* f2w = (const float*)d_in[9];
  const float* f2b = (const float*)d_in[10];

  char* ws = (char*)d_ws;
  u16*   imc  = (u16*)(ws + 0);            // 50331648 B (dead after k_dec)
  u16*   hs0  = (u16*)(ws + 50331648);     // 50331648 B (layer0 h seq = h state)
  u16*   zpage= (u16*)(ws + 100663296);    // 2 MB zero page / k_dec h scratch
  float* c0   = (float*)(ws + 102760448);  // 4 MB
  float* c1   = (float*)(ws + 106954752);  // 4 MB
  u16*   h1a  = (u16*)(ws + 111149056);    // 2 MB   [zpage..h1a = 12 MB zeroed]
  u16*   h1b  = (u16*)(ws + 113246208);    // 2 MB
  u16*   wp   = (u16*)(ws + 115343360);    // packed bf16 weights (311296 B)
  float* hdec = (float*)(ws + 117440512);  // 4 MB f32 NCHW
  float* part = (float*)(ws + 0);          // 1 MB, overlaps dead imc
  float* hdn  = (float*)(ws + 1048576);    // 8 KB,  overlaps dead imc
  u16 *Wh0p = wp, *Wx0p = wp + 36864, *Wx1p = wp + 40960, *Wh1p = wp + 77824,
      *Whdp = wp + 114688, *Wxdp = wp + 151552;

  k_pack<<<608, 256, 0, stream>>>(We0, We1, Wd, Wh0p, Wx0p, Wx1p, Wh1p, Whdp, Wxdp);
  k_im2col<<<3072, 256, 0, stream>>>(x, imc);
  k_zero<<<3072, 256, 0, stream>>>((uint4v*)zpage, 786432);   // zpage..h1a 12 MB

  for (int t = 0; t <= 24; ++t)
    k_dual<<<1024, 256, 0, stream>>>(t, imc, hs0, zpage, c0, h1a, h1b, c1,
                                     Wx0p, Wh0p, be0, Wx1p, Wh1p, be1);

  // layer1 final state: tt=23 (odd) -> written to h1a; c1 in place.
  // decoder scratch: h -> zpage (dead), c -> c0 (dead).
  k_dec<<<512, 256, 0, stream>>>(imc + (size_t)23 * 1048576, Wxdp, Whdp, bd,
                                 h1a, c1, zpage, c0, hdec);

  k_fc1<<<dim3(16, 128), 256, 0, stream>>>(f1w, hdec, part);
  k_fc1_fin<<<8, 256, 0, stream>>>(part, f1b, hdn);
  k_fc2<<<4, 256, 0, stream>>>(hdn, f2w, f2b, (float*)d_out);
}

// Round 4
// 542.136 us; speedup vs baseline: 1.8438x; 1.8438x over previous
//
#include <hip/hip_runtime.h>

typedef __attribute__((ext_vector_type(8))) short short8v;
typedef __attribute__((ext_vector_type(4))) float f32x4;
typedef __attribute__((ext_vector_type(4))) unsigned int uint4v;
typedef unsigned short u16;

__device__ __forceinline__ u16 f2bf(float f) {
  unsigned u = __float_as_uint(f);
  u += 0x7FFFu + ((u >> 16) & 1u);
  return (u16)(u >> 16);
}
__device__ __forceinline__ short8v ld8(const u16* p) {
  return *reinterpret_cast<const short8v*>(p);
}
__device__ __forceinline__ float fsig(float x) { return 1.f / (1.f + __expf(-x)); }
__device__ __forceinline__ float ftanh(float x) {
  float e = __expf(2.f * x);
  return 1.f - 2.f / (e + 1.f);
}

// ---------------- weight packing ---------------------------------------------
// Gate-local B layout: co' = cg*64 + gate*16 + chl  (ch = cg*16+chl, orig co =
// gate*32+ch). Shift tables: [s][cg][gate][16chl][32ci]; im2col: [cg][gate][16][32k].
__global__ void k_pack(const float* __restrict__ We0, const float* __restrict__ We1,
                       const float* __restrict__ Wd,
                       u16* __restrict__ Wh0p, u16* __restrict__ Wx1p,
                       u16* __restrict__ Wh1p, u16* __restrict__ Whdp,
                       u16* __restrict__ Wx0p, u16* __restrict__ Wxdp) {
  int i = blockIdx.x * 256 + threadIdx.x;   // total 155648
  if (i < 147456) {          // 4 shift-tables of 36864: Wh0, Wx1, Wh1, Whd
    int tbl = i / 36864, j = i % 36864;
    int s = j >> 12, cg = (j >> 11) & 1, gate = (j >> 9) & 3,
        chl = (j >> 5) & 15, ci = j & 31;
    int co = gate * 32 + cg * 16 + chl;
    float v;
    if (tbl == 0)      v = We0[(co * 35 + 3 + ci) * 9 + s];
    else if (tbl == 1) v = We1[(co * 64 + ci) * 9 + s];
    else if (tbl == 2) v = We1[(co * 64 + 32 + ci) * 9 + s];
    else               v = Wd[(co * 35 + 3 + ci) * 9 + s];
    u16* dst = tbl == 0 ? Wh0p : tbl == 1 ? Wx1p : tbl == 2 ? Wh1p : Whdp;
    dst[j] = f2bf(v);
  } else {                   // 2 im2col-tables of 4096: Wx0, Wxd
    int j = i - 147456, tbl = j >> 12;
    j &= 4095;
    int cg = (j >> 11) & 1, gate = (j >> 9) & 3, chl = (j >> 5) & 15, k = j & 31;
    int co = gate * 32 + cg * 16 + chl;
    const float* src = tbl ? Wd : We0;
    u16 v = (k < 27) ? f2bf(src[(co * 35 + (k % 3)) * 9 + (k / 3)]) : (u16)0;
    (tbl ? Wxdp : Wx0p)[j] = v;
  }
}

// ---------------- im2col of x for ALL frames: [t][b][y][x][32] bf16 ----------
__global__ void k_im2col(const float* __restrict__ x, u16* __restrict__ out) {
  int p = blockIdx.x * 256 + threadIdx.x;   // 786432 = 24*8*4096
  int t = p >> 15;
  int rem = p & 32767;
  int b = rem >> 12;
  int yy = (rem >> 6) & 63;
  int xx = rem & 63;
  __align__(16) u16 buf[32];
#pragma unroll
  for (int k = 27; k < 32; k++) buf[k] = 0;
  const float* xb = x + ((size_t)(b * 24 + t)) * 3 * 4096;
#pragma unroll
  for (int ky = 0; ky < 3; ky++) {
    int ys = yy + ky - 1;
    bool yok = (unsigned)ys < 64u;
#pragma unroll
    for (int kx = 0; kx < 3; kx++) {
      int xs = xx + kx - 1;
      bool ok = yok && ((unsigned)xs < 64u);
#pragma unroll
      for (int ci = 0; ci < 3; ci++) {
        float v = ok ? xb[(size_t)ci * 4096 + ys * 64 + xs] : 0.f;
        buf[(ky * 3 + kx) * 3 + ci] = f2bf(v);
      }
    }
  }
  uint4v* dst = (uint4v*)(out + (size_t)p * 32);
  const uint4v* s = (const uint4v*)buf;
  dst[0] = s[0]; dst[1] = s[1]; dst[2] = s[2]; dst[3] = s[3];
}

__global__ void k_zero(uint4v* __restrict__ p, int n) {
  int i = blockIdx.x * 256 + threadIdx.x;
  if (i < n) p[i] = (uint4v)0u;
}

// ---------------- fused ConvLSTM step body ----------------------------------
// Block = 2 rows (128 px). Wave w: row y0+(w>>1), channel-group cg=w&1
// (channels cg*16..+16), 4 m-tiles x 4 gate-n-tiles = 144 MFMA, 36 B-loads.
// Gates thread-local: lane lr <-> channel, acc[mt][gate][j] <-> px.
// LDS staging g-major: sm[(r*4+gq)*66 + px+1][8] -> conflict-free b128 r/w.
template <int MODE>
__device__ __forceinline__ void step_body(
    u16* sm_h, u16* sm_x, int bid,
    const u16* __restrict__ xA, const u16* __restrict__ Wx,
    const u16* __restrict__ Wh, const float* __restrict__ bias,
    const u16* __restrict__ hprev, const float* __restrict__ cprev,
    u16* __restrict__ hout, float* __restrict__ cout,
    float* __restrict__ hdec) {
  const int tid = threadIdx.x;
  const int b = bid >> 5;
  const int y0 = (bid & 31) << 1;
  const int l = tid & 63;
  const int w = tid >> 6;
  const int lr = l & 15;
  const int g = l >> 4;
  const int mh = w >> 1;
  const int cg = w & 1;
  const int y = y0 + mh;

  // zero the px=0 / px=65 pad slots
  if (tid < (MODE == 1 ? 64 : 32)) {
    int op = tid >> 5, q = tid & 31;
    int r = q >> 3, gq = (q >> 1) & 3, side = q & 1;
    *(uint4v*)((op ? sm_x : sm_h) + ((size_t)((r * 4 + gq) * 66 + side * 65)) * 8) =
        (uint4v)0u;
  }
  const int nch = (MODE == 1) ? 2048 : 1024;
  for (int i = tid; i < nch; i += 256) {
    int ii = i & 1023;
    int r = ii >> 8, rem = ii & 255;
    int px = rem >> 2, gq = rem & 3;
    int ys = y0 - 1 + r;
    const u16* src = (i < 1024) ? hprev : xA;
    u16* dst = (i < 1024) ? sm_h : sm_x;
    uint4v v = (uint4v)0u;
    if ((unsigned)ys < 64u)
      v = *(const uint4v*)(src + ((size_t)((b * 64 + ys) * 64 + px)) * 32 + gq * 8);
    *(uint4v*)(dst + ((size_t)((r * 4 + gq) * 66 + px + 1)) * 8) = v;
  }
  __syncthreads();

  f32x4 acc[4][4];
#pragma unroll
  for (int i = 0; i < 4; i++)
#pragma unroll
    for (int j = 0; j < 4; j++) acc[i][j] = (f32x4)0.f;

  if (MODE == 0 || MODE == 2) {
    // im2col K=32 chunk (k padded to 32); B: [cg][gate][16][32]
    const u16* ab = xA + (size_t)((b * 64 + y) * 64) * 32 + g * 8;
    const u16* wb = Wx + (cg * 64 + lr) * 32 + g * 8;
    short8v B0 = ld8(wb), B1 = ld8(wb + 512), B2 = ld8(wb + 1024), B3 = ld8(wb + 1536);
#pragma unroll
    for (int mt = 0; mt < 4; mt++) {
      short8v A = ld8(ab + (mt * 16 + lr) * 32);
      acc[mt][0] = __builtin_amdgcn_mfma_f32_16x16x32_bf16(A, B0, acc[mt][0], 0, 0, 0);
      acc[mt][1] = __builtin_amdgcn_mfma_f32_16x16x32_bf16(A, B1, acc[mt][1], 0, 0, 0);
      acc[mt][2] = __builtin_amdgcn_mfma_f32_16x16x32_bf16(A, B2, acc[mt][2], 0, 0, 0);
      acc[mt][3] = __builtin_amdgcn_mfma_f32_16x16x32_bf16(A, B3, acc[mt][3], 0, 0, 0);
    }
  }

  auto do_shifts = [&](const u16* sm, const u16* __restrict__ W) {
#pragma unroll
    for (int s = 0; s < 9; s++) {
      const int ky = s / 3, dx = s % 3 - 1;
      const u16* wb = W + ((size_t)(s * 2 + cg) * 64 + lr) * 32 + g * 8;
      short8v B0 = ld8(wb), B1 = ld8(wb + 512), B2 = ld8(wb + 1024), B3 = ld8(wb + 1536);
      const u16* abase = sm + ((size_t)(((mh + ky) * 4 + g) * 66 + lr + dx + 1)) * 8;
#pragma unroll
      for (int mt = 0; mt < 4; mt++) {
        short8v A = ld8(abase + mt * 128);   // 16 px * 8 elems
        acc[mt][0] = __builtin_amdgcn_mfma_f32_16x16x32_bf16(A, B0, acc[mt][0], 0, 0, 0);
        acc[mt][1] = __builtin_amdgcn_mfma_f32_16x16x32_bf16(A, B1, acc[mt][1], 0, 0, 0);
        acc[mt][2] = __builtin_amdgcn_mfma_f32_16x16x32_bf16(A, B2, acc[mt][2], 0, 0, 0);
        acc[mt][3] = __builtin_amdgcn_mfma_f32_16x16x32_bf16(A, B3, acc[mt][3], 0, 0, 0);
      }
    }
  };

  if (MODE == 1) do_shifts(sm_x, Wx);
  do_shifts(sm_h, Wh);

  // gates fully thread-local: ch = cg*16+lr, px = mt*16 + g*4 + j
  const int ch = cg * 16 + lr;
  const float bI = bias[ch], bF = bias[32 + ch], bO = bias[64 + ch], bG = bias[96 + ch];
  const size_t rowbase = (size_t)((b * 64 + y) * 64) * 32 + ch;
#pragma unroll
  for (int mt = 0; mt < 4; mt++) {
#pragma unroll
    for (int j = 0; j < 4; j++) {
      int px = mt * 16 + g * 4 + j;
      size_t base = rowbase + (size_t)px * 32;
      float cold = cprev[base];
      float cn = fsig(acc[mt][1][j] + bF) * cold +
                 fsig(acc[mt][0][j] + bI) * ftanh(acc[mt][3][j] + bG);
      float hn = fsig(acc[mt][2][j] + bO) * ftanh(cn);
      cout[base] = cn;
      hout[base] = f2bf(hn);
      if (MODE == 2) hdec[((size_t)(b * 32 + ch) * 64 + y) * 64 + px] = hn;
    }
  }
}

// dual-layer: blocks 0..255 = layer0 step t, 256..511 = layer1 step t-1
__global__ __launch_bounds__(256, 2) void k_dual(
    int t, const u16* __restrict__ imc, u16* __restrict__ hs0,
    const u16* __restrict__ zpage, float* c0, u16* h1a, u16* h1b, float* c1,
    const u16* __restrict__ Wx0, const u16* __restrict__ Wh0, const float* __restrict__ be0,
    const u16* __restrict__ Wx1, const u16* __restrict__ Wh1, const float* __restrict__ be1) {
  __shared__ __align__(16) u16 smem[16896];   // 33792 B
  int bid = blockIdx.x;
  if (bid < 256) {
    if (t >= 24) return;
    const u16* hp = (t == 0) ? zpage : hs0 + (size_t)(t - 1) * 1048576;
    step_body<0>(smem, nullptr, bid, imc + (size_t)t * 1048576, Wx0, Wh0, be0,
                 hp, c0, hs0 + (size_t)t * 1048576, c0, nullptr);
  } else {
    int tt = t - 1;
    if (tt < 0) return;
    const u16* hp = (tt & 1) ? h1b : h1a;
    u16* hn = (tt & 1) ? h1a : h1b;
    step_body<1>(smem, smem + 8448, bid - 256, hs0 + (size_t)tt * 1048576,
                 Wx1, Wh1, be1, hp, c1, hn, c1, nullptr);
  }
}

__global__ __launch_bounds__(256, 2) void k_dec(
    const u16* __restrict__ imc23, const u16* __restrict__ Wxd,
    const u16* __restrict__ Whd, const float* __restrict__ bd,
    const u16* __restrict__ h1fin, const float* __restrict__ c1,
    u16* __restrict__ hscr, float* __restrict__ cscr, float* __restrict__ hdec) {
  __shared__ __align__(16) u16 smem[8448];    // 16896 B
  step_body<2>(smem, nullptr, blockIdx.x, imc23, Wxd, Whd, bd, h1fin, c1,
               hscr, cscr, hdec);
}

// ---------------- FC head ---------------------------------------------------
__global__ __launch_bounds__(256) void k_fc1(const float* __restrict__ w,
                                             const float* __restrict__ feat,
                                             float* __restrict__ partial) {
  __shared__ float fsm[8][1024];   // 32 KB
  const int ng = blockIdx.x, ks = blockIdx.y;
  const int tid = threadIdx.x;
  const float* fb = feat + (size_t)ks * 1024;
  for (int i = tid; i < 2048; i += 256) {
    int bb = i >> 8, kk = (i & 255) << 2;
    *(f32x4*)&fsm[bb][kk] = *(const f32x4*)(fb + (size_t)bb * 131072 + kk);
  }
  __syncthreads();
  const int wv = tid >> 6, lane = tid & 63;
  const int n0 = ng * 16 + wv * 4;
  const float* wr = w + (size_t)n0 * 131072 + (size_t)ks * 1024;
  float acc[4][8];
#pragma unroll
  for (int i = 0; i < 4; i++)
#pragma unroll
    for (int j = 0; j < 8; j++) acc[i][j] = 0.f;
#pragma unroll
  for (int it = 0; it < 4; it++) {
    int k = it * 256 + lane * 4;
    f32x4 w0 = *(const f32x4*)(wr + k);
    f32x4 w1 = *(const f32x4*)(wr + 131072 + k);
    f32x4 w2 = *(const f32x4*)(wr + 262144 + k);
    f32x4 w3 = *(const f32x4*)(wr + 393216 + k);
#pragma unroll
    for (int bb = 0; bb < 8; bb++) {
      f32x4 fv = *(const f32x4*)&fsm[bb][k];
      acc[0][bb] += w0[0] * fv[0] + w0[1] * fv[1] + w0[2] * fv[2] + w0[3] * fv[3];
      acc[1][bb] += w1[0] * fv[0] + w1[1] * fv[1] + w1[2] * fv[2] + w1[3] * fv[3];
      acc[2][bb] += w2[0] * fv[0] + w2[1] * fv[1] + w2[2] * fv[2] + w2[3] * fv[3];
      acc[3][bb] += w3[0] * fv[0] + w3[1] * fv[1] + w3[2] * fv[2] + w3[3] * fv[3];
    }
  }
#pragma unroll
  for (int nn = 0; nn < 4; nn++)
#pragma unroll
    for (int bb = 0; bb < 8; bb++) {
      float v = acc[nn][bb];
#pragma unroll
      for (int m = 32; m >= 1; m >>= 1) v += __shfl_xor(v, m, 64);
      if (lane == 0) partial[((size_t)ks * 8 + bb) * 256 + n0 + nn] = v;
    }
}

__global__ void k_fc1_fin(const float* __restrict__ partial,
                          const float* __restrict__ b1, float* __restrict__ hdn) {
  int i = blockIdx.x * 256 + threadIdx.x;  // 2048
  if (i >= 2048) return;
  int b = i >> 8, n = i & 255;
  float v = b1[n];
  for (int ks = 0; ks < 128; ks++) v += partial[((size_t)ks * 8 + b) * 256 + n];
  hdn[i] = fmaxf(v, 0.f);
}

__global__ void k_fc2(const float* __restrict__ hdn, const float* __restrict__ w2,
                      const float* __restrict__ b2, float* __restrict__ out) {
  int i = blockIdx.x * 256 + threadIdx.x;  // 776 = 8*97
  if (i >= 776) return;
  int b = i / 97, m = i % 97;
  const float* h = hdn + b * 256;
  const float* wr = w2 + m * 256;
  float v = b2[m];
  for (int k = 0; k < 256; k++) v += h[k] * wr[k];
  out[i] = v;
}

// ---------------- launcher ---------------------------------------------------
extern "C" void kernel_launch(void* const* d_in, const int* in_sizes, int n_in,
                              void* d_out, int out_size, void* d_ws, size_t ws_size,
                              hipStream_t stream) {
  const float* x   = (const float*)d_in[0];
  const float* We0 = (const float*)d_in[1];
  const float* be0 = (const float*)d_in[2];
  const float* We1 = (const float*)d_in[3];
  const float* be1 = (const float*)d_in[4];
  const float* Wd  = (const float*)d_in[5];
  const float* bd  = (const float*)d_in[6];
  const float* f1w = (const float*)d_in[7];
  const float* f1b = (const float*)d_in[8];
  const float* f2w = (const float*)d_in[9];
  const float* f2b = (const float*)d_in[10];

  char* ws = (char*)d_ws;
  u16*   imc  = (u16*)(ws + 0);            // 50331648 B (dead after k_dec)
  u16*   hs0  = (u16*)(ws + 50331648);     // 50331648 B
  u16*   zpage= (u16*)(ws + 100663296);    // 2 MB zero page / k_dec h scratch
  float* c0   = (float*)(ws + 102760448);  // 4 MB
  float* c1   = (float*)(ws + 106954752);  // 4 MB
  u16*   h1a  = (u16*)(ws + 111149056);    // 2 MB  [zpage..h1a = 12 MB zeroed]
  u16*   h1b  = (u16*)(ws + 113246208);    // 2 MB
  u16*   wp   = (u16*)(ws + 115343360);    // packed bf16 weights
  float* hdec = (float*)(ws + 117440512);  // 4 MB f32 NCHW
  float* part = (float*)(ws + 0);          // 1 MB, overlaps dead imc
  float* hdn  = (float*)(ws + 1048576);    // 8 KB, overlaps dead imc
  u16 *Wh0p = wp, *Wx1p = wp + 36864, *Wh1p = wp + 73728, *Whdp = wp + 110592,
      *Wx0p = wp + 147456, *Wxdp = wp + 151552;

  k_pack<<<608, 256, 0, stream>>>(We0, We1, Wd, Wh0p, Wx1p, Wh1p, Whdp, Wx0p, Wxdp);
  k_im2col<<<3072, 256, 0, stream>>>(x, imc);
  k_zero<<<3072, 256, 0, stream>>>((uint4v*)zpage, 786432);   // zpage..h1a 12 MB

  for (int t = 0; t <= 24; ++t)
    k_dual<<<512, 256, 0, stream>>>(t, imc, hs0, zpage, c0, h1a, h1b, c1,
                                    Wx0p, Wh0p, be0, Wx1p, Wh1p, be1);

  // layer1 final state: tt=23 -> h1a; c1 in place. Decoder scratch: zpage/c0 (dead).
  k_dec<<<256, 256, 0, stream>>>(imc + (size_t)23 * 1048576, Wxdp, Whdp, bd,
                                 h1a, c1, zpage, c0, hdec);

  k_fc1<<<dim3(16, 128), 256, 0, stream>>>(f1w, hdec, part);
  k_fc1_fin<<<8, 256, 0, stream>>>(part, f1b, hdn);
  k_fc2<<<4, 256, 0, stream>>>(hdn, f2w, f2b, (float*)d_out);
}